// Round 12
// baseline (280.563 us; speedup 1.0000x reference)
//
#include <hip/hip_runtime.h>
#include <cstdint>
#include <cstddef>

typedef short s8v __attribute__((ext_vector_type(8)));
typedef short s4v __attribute__((ext_vector_type(4)));
typedef float f4v __attribute__((ext_vector_type(4)));

static __device__ __forceinline__ float b2f(short s){
  return __uint_as_float(((uint32_t)(uint16_t)s) << 16);
}
static __device__ __forceinline__ short f2bf(float f){
  uint32_t u = __float_as_uint(f);
  u = (u + 0x7fffu + ((u >> 16) & 1u)) >> 16;
  return (short)(uint16_t)u;
}
// async global->LDS, 16B per lane, LDS dest = uniform base + lane*16
static __device__ __forceinline__ void gld_lds16(const void* g, void* l){
  __builtin_amdgcn_global_load_lds((const __attribute__((address_space(1))) void*)g,
                                   (__attribute__((address_space(3))) void*)l, 16, 0, 0);
}

// ---- graph prep (fused) ----
__global__ void k_deg(const int* __restrict__ tgt, int* __restrict__ deg, int nE){
  int e = blockIdx.x*blockDim.x + threadIdx.x;
  if(e < nE) atomicAdd(&deg[tgt[e]], 1);
}

#define SCAN_BS 256
__global__ void k_scan1_dinv(const int* __restrict__ deg, int* __restrict__ rowptr,
                             int* __restrict__ blocksum, float* __restrict__ dinv, int nN){
  __shared__ int tmp[SCAN_BS];
  const int t = threadIdx.x;
  const int i = blockIdx.x*SCAN_BS + t;
  int v = (i < nN) ? deg[i] : 0;
  if(i < nN) dinv[i] = rsqrtf((float)v + 1.0f);   // +1 self-loop
  tmp[t] = v; __syncthreads();
  #pragma unroll
  for(int off=1; off<SCAN_BS; off<<=1){
    int x = (t >= off) ? tmp[t-off] : 0;
    __syncthreads();
    tmp[t] += x;
    __syncthreads();
  }
  if(i < nN) rowptr[i] = tmp[t] - v;
  if(t == SCAN_BS-1) blocksum[blockIdx.x] = tmp[t];
}
__global__ void k_scan2_bounds(int* __restrict__ blocksum, int nb,
                               const int* __restrict__ batch, int* __restrict__ gstart,
                               int nN, int nG){
  __shared__ int tmp[1024];
  const int t = threadIdx.x;
  int v = (t < nb) ? blocksum[t] : 0;
  tmp[t] = v; __syncthreads();
  #pragma unroll
  for(int off=1; off<1024; off<<=1){
    int x = (t >= off) ? tmp[t-off] : 0;
    __syncthreads();
    tmp[t] += x;
    __syncthreads();
  }
  if(t < nb) blocksum[t] = tmp[t] - v;
  if(t <= nG){
    int lo = 0, hi = nN;
    while(lo < hi){
      int mid = (lo + hi) >> 1;
      if(batch[mid] < t) lo = mid + 1; else hi = mid;
    }
    gstart[t] = lo;
  }
}
__global__ void k_scan3(int* __restrict__ rowptr, const int* __restrict__ blocksum,
                        int nN, int nE){
  const int i = blockIdx.x*SCAN_BS + threadIdx.x;
  if(i < nN) rowptr[i] += blocksum[blockIdx.x];
  if(i == 0) rowptr[nN] = nE;
}
__global__ void k_fill(const int* __restrict__ src, const int* __restrict__ tgt,
                       const int* __restrict__ rowptr, int* __restrict__ cursor,
                       int* __restrict__ csr_src, float* __restrict__ csr_w,
                       const float* __restrict__ dinv, int nE){
  int e = blockIdx.x*blockDim.x + threadIdx.x;
  if(e >= nE) return;
  int t = tgt[e];
  int s = src[e];
  int pos = rowptr[t] + atomicAdd(&cursor[t], 1);
  csr_src[pos] = s;
  csr_w[pos] = dinv[s] * dinv[t];
}
__global__ void k_transpose_cvt2(const float* __restrict__ W1, short* __restrict__ W1T,
                                 int K1, const float* __restrict__ W2, short* __restrict__ W2T,
                                 int K2, int N){
  int g = blockIdx.x*blockDim.x + threadIdx.x;
  const int t1 = K1*N;
  if(g < t1){
    int n = g / K1, k = g % K1;
    W1T[(size_t)n*K1 + k] = f2bf(W1[(size_t)k*N + n]);
  } else {
    g -= t1;
    if(g >= K2*N) return;
    int n = g / K2, k = g % K2;
    W2T[(size_t)n*K2 + k] = f2bf(W2[(size_t)k*N + n]);
  }
}

// ---- slab GEMM: linear single-touch A stream + LDS-pipelined B ----
// C[m][n] = sum_k A[m][k]*Bt[n][k]. Block = 32 A-rows x ALL 256 cols, 4 waves
// (wave wv owns cols [wv*64, wv*64+64)).
// Phase 1: the CONTIGUOUS 32-row A slab (96KB f32 / 16KB bf16) is streamed
//   linearly global->reg->bf16->XOR-swizzled LDS (no barriers mid-stream).
// Phase 2: K-loop; per chunk kc (KC=32), B tile (256x32, 16KB) is staged via
//   global_load_lds issue-early/use-late: STAGE_B(kc+1) right after barrier(kc)
//   so compute(kc) hides the L2 latency (W is 384KB, L2-resident).
//   NBUF=2 safety: after barrier(kc) no wave can still read slot (kc+1)&1
//   (compute(kc-1) precedes barrier(kc) in program order).
// LDS: A 48KB (max) + B 2x16KB = 80KB -> 2 blocks/CU.
template<bool AF32>
__global__ __launch_bounds__(256) void gemm_slab(const void* __restrict__ Ap,
    const short* __restrict__ Bt, short* __restrict__ C, int M, int N, int K)
{
  __shared__ __align__(16) short A_lds[32*768];   // 48 KB (K<=768)
  __shared__ __align__(16) char  Bs[2][256*64];   // 32 KB
  const int tid  = threadIdx.x;
  const int lane = tid & 63;
  const int wv   = tid >> 6;
  const int lr   = lane & 15;
  const int hi   = lane >> 4;
  const int row0 = blockIdx.x * 32;
  const int RS   = K*2;                 // LDS A row stride (bytes)
  const int nkc  = K/32;                // 24 | 8
  const int NSTEP= (32*RS)/4096;        // dest steps: 12 | 4 (256thr x 16B)

  // B staging lane geometry (round-6 verified swizzle scheme)
  const int w_ch = lane & 3;
  const int w_ro = lane >> 2;
  auto STAGE_B = [&](int kc, int buf){
    #pragma unroll
    for(int j=0;j<4;j++){
      const int cbase = wv*64 + j*16;
      const int col = cbase + w_ro;
      const int sch = w_ch ^ ((col>>1) & 3);
      const char* g = (const char*)Bt + ((size_t)col*K + (size_t)kc*32)*2 + (sch<<4);
      gld_lds16(g, (void*)(Bs[buf] + cbase*64));
    }
  };

  STAGE_B(0, 0);   // lands while A streams

  // ---- Phase 1: linear A slab stage ----
  {
    const char* Abase = (const char*)Ap + (size_t)row0 * K * (AF32?4:2);
    char* L = (char*)A_lds;
    auto dsw = [&](int db)->int{           // swizzled dest byte for linear dest db
      int row = db / RS;
      int slot = (db - row*RS) >> 4;
      return row*RS + ((slot ^ (row & 7)) << 4);
    };
    if constexpr(AF32){
      f4v P0{},P1{},Q0{},Q1{};
      auto LD = [&](int st, f4v& r0, f4v& r1){
        int db = st*4096 + tid*16;
        if(row0 + db/RS < M){
          r0 = *(const f4v*)(Abase + 2*(size_t)db);
          r1 = *(const f4v*)(Abase + 2*(size_t)db + 16);
        } else {
          for(int q=0;q<4;q++){ r0[q]=0.f; r1[q]=0.f; }
        }
      };
      auto WR = [&](int st, f4v& r0, f4v& r1){
        int db = st*4096 + tid*16;
        s8v v;
        #pragma unroll
        for(int q=0;q<4;q++){ v[q] = f2bf(r0[q]); v[4+q] = f2bf(r1[q]); }
        *(s8v*)(L + dsw(db)) = v;
      };
      LD(0,P0,P1);
      for(int st=0; st<NSTEP; st+=2){
        LD(st+1,Q0,Q1);
        WR(st,P0,P1);
        if(st+2<NSTEP) LD(st+2,P0,P1);
        WR(st+1,Q0,Q1);
      }
    } else {
      s8v P{},Q{};
      auto LD = [&](int st, s8v& r){
        int db = st*4096 + tid*16;
        if(row0 + db/RS < M){
          r = *(const s8v*)(Abase + db);
        } else {
          for(int q=0;q<8;q++) r[q]=0;
        }
      };
      auto WR = [&](int st, s8v& r){
        int db = st*4096 + tid*16;
        *(s8v*)(L + dsw(db)) = r;
      };
      LD(0,P);
      for(int st=0; st<NSTEP; st+=2){
        LD(st+1,Q);
        WR(st,P);
        if(st+2<NSTEP) LD(st+2,P);
        WR(st+1,Q);
      }
    }
  }
  __syncthreads();   // A resident; drains everything incl. B chunk 0

  // ---- Phase 2: K-loop ----
  f4v acc[2][4];
  #pragma unroll
  for(int s=0;s<2;s++)
    #pragma unroll
    for(int nf=0;nf<4;nf++){ acc[s][nf][0]=0.f; acc[s][nf][1]=0.f; acc[s][nf][2]=0.f; acc[s][nf][3]=0.f; }

  const char* L = (const char*)A_lds;

  for(int kc=0; kc<nkc; kc++){
    asm volatile("s_waitcnt vmcnt(0)" ::: "memory");   // B(kc) landed (own loads)
    __builtin_amdgcn_s_barrier();                      // all waves' B(kc) visible
    __builtin_amdgcn_sched_barrier(0);
    if(kc+1 < nkc) STAGE_B(kc+1, (kc+1)&1);            // hide under compute(kc)

    const char* bb = Bs[kc&1];

    s8v a[2];
    #pragma unroll
    for(int s=0;s<2;s++){
      const int row = s*16 + lr;
      const int chunk = kc*4 + hi;
      a[s] = *(const s8v*)(L + row*RS + ((chunk ^ (row&7))<<4));
    }

    #pragma unroll
    for(int nf=0;nf<4;nf++){
      const int brow = wv*64 + nf*16 + lr;
      const int c = hi ^ ((brow>>1) & 3);
      s8v bfr = *(const s8v*)(bb + brow*64 + (c<<4));
      acc[0][nf] = __builtin_amdgcn_mfma_f32_16x16x32_bf16(a[0], bfr, acc[0][nf], 0, 0, 0);
      acc[1][nf] = __builtin_amdgcn_mfma_f32_16x16x32_bf16(a[1], bfr, acc[1][nf], 0, 0, 0);
    }
  }

  // epilogue: row = row0 + s*16 + hi*4 + j, col = wv*64 + nf*16 + lr
  #pragma unroll
  for(int s=0;s<2;s++){
    #pragma unroll
    for(int j=0;j<4;j++){
      const int row = row0 + s*16 + hi*4 + j;
      if(row >= M) continue;
      #pragma unroll
      for(int nf=0;nf<4;nf++){
        const int col = wv*64 + nf*16 + lr;
        C[(size_t)row*N + col] = f2bf(acc[s][nf][j]);
      }
    }
  }
}

// ---- fused aggregation: one wave per node, coalesced idx/weight prefetch + 8-deep gather ----
__global__ __launch_bounds__(256) void k_aggregate(
    const short* __restrict__ h, const float* __restrict__ dinv,
    const int* __restrict__ rowptr, const int* __restrict__ csr_src,
    const float* __restrict__ csr_w, const float* __restrict__ bias,
    short* __restrict__ hout, int nN)
{
  const int wave = threadIdx.x >> 6;
  const int lane = threadIdx.x & 63;
  const int node = blockIdx.x*4 + wave;
  if(node >= nN) return;
  const float di = dinv[node];
  const int beg = rowptr[node];
  const int deg = rowptr[node+1] - beg;

  s4v hv = *(const s4v*)&h[(size_t)node*256 + lane*4];
  const float d2 = di*di;
  f4v acc;
  #pragma unroll
  for(int j=0;j<4;j++) acc[j] = d2 * b2f(hv[j]);

  for(int base=0; base<deg; base+=64){
    const int cnt = min(deg - base, 64);
    int   myi = (lane < cnt) ? csr_src[beg + base + lane] : 0;
    float myw = (lane < cnt) ? csr_w[beg + base + lane] : 0.f;

    for(int p0=0; p0<cnt; p0+=8){
      s4v v[8]; float w[8]; int s[8];
      #pragma unroll
      for(int j=0;j<8;j++){
        int pp = p0 + j;
        int sl = (pp < cnt) ? pp : 0;
        s[j] = __shfl(myi, sl);
        w[j] = (pp < cnt) ? __shfl(myw, sl) : 0.f;
      }
      #pragma unroll
      for(int j=0;j<8;j++)
        v[j] = *(const s4v*)&h[(size_t)s[j]*256 + lane*4];
      #pragma unroll
      for(int j=0;j<8;j++){
        #pragma unroll
        for(int q=0;q<4;q++) acc[q] += w[j] * b2f(v[j][q]);
      }
    }
  }

  f4v bv = *(const f4v*)&bias[lane*4];
  s4v ov;
  #pragma unroll
  for(int j=0;j<4;j++) ov[j] = f2bf(fmaxf(acc[j]+bv[j], 0.f));
  *(s4v*)&hout[(size_t)node*256 + lane*4] = ov;
}

// ---- mean-pool: per-(graph,slice) partial sums, no atomics, no memset ----
#define POOL_SPLIT 8
__global__ __launch_bounds__(256) void k_pool(const short* __restrict__ h,
    const int* __restrict__ gstart, float* __restrict__ pool, int nG){
  const int g = blockIdx.x;
  const int sl = blockIdx.y;
  const int c = threadIdx.x;
  const int b = gstart[g], e = gstart[g+1];
  const int len = e - b;
  const int r0 = b + (int)((long long)len * sl / POOL_SPLIT);
  const int r1 = b + (int)((long long)len * (sl+1) / POOL_SPLIT);
  float acc = 0.f;
  for(int r=r0; r<r1; r++) acc += b2f(h[(size_t)r*256 + c]);
  pool[((size_t)g*POOL_SPLIT + sl)*256 + c] = acc;
}

__global__ void k_final(const float* __restrict__ pool, const int* __restrict__ gstart,
                        const float* __restrict__ Wp, const float* __restrict__ bp,
                        float* __restrict__ out, int HID_, int OUT_){
  __shared__ float mean[256];
  int g = blockIdx.x, j = threadIdx.x;
  float c = fmaxf((float)(gstart[g+1] - gstart[g]), 1.0f);
  for(int k=j; k<HID_; k+=blockDim.x){
    float s = 0.f;
    #pragma unroll
    for(int sl=0; sl<POOL_SPLIT; sl++)
      s += pool[((size_t)g*POOL_SPLIT + sl)*HID_ + k];
    mean[k] = s / c;
  }
  __syncthreads();
  float acc = bp[j];
  for(int k=0;k<HID_;k++) acc = fmaf(mean[k], Wp[(size_t)k*OUT_ + j], acc);
  out[(size_t)g*OUT_ + j] = acc;
}

extern "C" void kernel_launch(void* const* d_in, const int* in_sizes, int n_in,
                              void* d_out, int out_size, void* d_ws, size_t ws_size,
                              hipStream_t stream){
  const float* x   = (const float*)d_in[0];
  const int* ei    = (const int*)d_in[1];
  const int* batch = (const int*)d_in[2];
  const float* W1  = (const float*)d_in[3];
  const float* b1  = (const float*)d_in[4];
  const float* W2  = (const float*)d_in[5];
  const float* b2  = (const float*)d_in[6];
  const float* Wp  = (const float*)d_in[7];
  const float* bp  = (const float*)d_in[8];
  float* out = (float*)d_out;

  const int HID    = in_sizes[4];            // 256
  const int IN_DIM = in_sizes[3] / HID;      // 768
  const int OUT    = in_sizes[8];            // 128
  const int nE     = in_sizes[1] / 2;        // 300000
  const int nN     = in_sizes[2];            // 50000
  const int nG     = out_size / OUT;         // 64

  const int* src = ei;
  const int* tgt = ei + nE;

  char* w = (char*)d_ws;
  size_t off = 0;
  auto alloc = [&](size_t bytes)->char*{
    char* p = w + off; off += (bytes + 511) & ~(size_t)511; return p;
  };
  int*   deg     = (int*)  alloc((size_t)nN*4);      // deg+cursor adjacent: one memset
  int*   cursor  = (int*)  alloc((size_t)nN*4);
  float* dinv    = (float*)alloc((size_t)nN*4);
  int*   gstart  = (int*)  alloc((size_t)(nG+1)*4);
  float* pool    = (float*)alloc((size_t)nG*POOL_SPLIT*HID*4);
  int*   rowptr  = (int*)  alloc((size_t)(nN+1)*4);
  int*   csr_src = (int*)  alloc((size_t)nE*4);
  float* csr_w   = (float*)alloc((size_t)nE*4);
  int*   blocksum= (int*)  alloc((size_t)1024*4);
  short* W1T     = (short*)alloc((size_t)IN_DIM*HID*2);
  short* W2T     = (short*)alloc((size_t)HID*HID*2);
  short* h1      = (short*)alloc((size_t)(nN+128)*HID*2);
  short* h2      = (short*)alloc((size_t)(nN+128)*HID*2);
  (void)ws_size; (void)n_in;

  hipMemsetAsync(deg, 0, (size_t)((char*)cursor - (char*)deg) + (size_t)nN*4, stream);

  const int nb = (nN + SCAN_BS - 1) / SCAN_BS;
  k_deg <<<(nE+255)/256, 256, 0, stream>>>(tgt, deg, nE);
  k_scan1_dinv<<<nb, SCAN_BS, 0, stream>>>(deg, rowptr, blocksum, dinv, nN);
  k_scan2_bounds<<<1, 1024, 0, stream>>>(blocksum, nb, batch, gstart, nN, nG);
  k_scan3<<<nb, SCAN_BS, 0, stream>>>(rowptr, blocksum, nN, nE);
  k_fill <<<(nE+255)/256, 256, 0, stream>>>(src, tgt, rowptr, cursor, csr_src, csr_w, dinv, nE);
  k_transpose_cvt2<<<((IN_DIM+HID)*HID+255)/256, 256, 0, stream>>>(W1, W1T, IN_DIM, W2, W2T, HID, HID);

  const int ngb = (nN + 31) / 32;
  const int nagg = (nN + 3) / 4;
  // layer 1
  gemm_slab<true><<<ngb, 256, 0, stream>>>(x, W1T, h2, nN, HID, IN_DIM);
  k_aggregate<<<nagg, 256, 0, stream>>>(h2, dinv, rowptr, csr_src, csr_w, b1, h1, nN);
  // layer 2
  gemm_slab<false><<<ngb, 256, 0, stream>>>(h1, W2T, h2, nN, HID, HID);
  k_aggregate<<<nagg, 256, 0, stream>>>(h2, dinv, rowptr, csr_src, csr_w, b2, h1, nN);
  k_pool<<<dim3(nG, POOL_SPLIT), 256, 0, stream>>>(h1, gstart, pool, nG);
  // head
  k_final<<<nG, OUT, 0, stream>>>(pool, gstart, Wp, bp, out, HID, OUT);
}

// Round 13
// 278.501 us; speedup vs baseline: 1.0074x; 1.0074x over previous
//
#include <hip/hip_runtime.h>
#include <cstdint>
#include <cstddef>

typedef short s8v __attribute__((ext_vector_type(8)));
typedef short s4v __attribute__((ext_vector_type(4)));
typedef float f4v __attribute__((ext_vector_type(4)));

static __device__ __forceinline__ float b2f(short s){
  return __uint_as_float(((uint32_t)(uint16_t)s) << 16);
}
static __device__ __forceinline__ short f2bf(float f){
  uint32_t u = __float_as_uint(f);
  u = (u + 0x7fffu + ((u >> 16) & 1u)) >> 16;
  return (short)(uint16_t)u;
}
// async global->LDS, 16B per lane, LDS dest = uniform base + lane*16
static __device__ __forceinline__ void gld_lds16(const void* g, void* l){
  __builtin_amdgcn_global_load_lds((const __attribute__((address_space(1))) void*)g,
                                   (__attribute__((address_space(3))) void*)l, 16, 0, 0);
}

// ---- pure streaming f32 -> bf16 convert (linear, no barriers: copy-BW pattern) ----
__global__ __launch_bounds__(256) void k_convert(const float* __restrict__ x,
                                                 short* __restrict__ xb, long n){
  long i = ((long)blockIdx.x*blockDim.x + threadIdx.x)*16;
  const long stride = (long)gridDim.x*blockDim.x*16;
  for(; i < n; i += stride){
    f4v a0 = *(const f4v*)(x+i);
    f4v a1 = *(const f4v*)(x+i+4);
    f4v a2 = *(const f4v*)(x+i+8);
    f4v a3 = *(const f4v*)(x+i+12);
    s8v v0, v1;
    #pragma unroll
    for(int q=0;q<4;q++){
      v0[q] = f2bf(a0[q]); v0[4+q] = f2bf(a1[q]);
      v1[q] = f2bf(a2[q]); v1[4+q] = f2bf(a3[q]);
    }
    *(s8v*)(xb+i)   = v0;
    *(s8v*)(xb+i+8) = v1;
  }
}

// ---- graph prep (fused) ----
__global__ void k_deg(const int* __restrict__ tgt, int* __restrict__ deg, int nE){
  int e = blockIdx.x*blockDim.x + threadIdx.x;
  if(e < nE) atomicAdd(&deg[tgt[e]], 1);
}

#define SCAN_BS 256
__global__ void k_scan1_dinv(const int* __restrict__ deg, int* __restrict__ rowptr,
                             int* __restrict__ blocksum, float* __restrict__ dinv, int nN){
  __shared__ int tmp[SCAN_BS];
  const int t = threadIdx.x;
  const int i = blockIdx.x*SCAN_BS + t;
  int v = (i < nN) ? deg[i] : 0;
  if(i < nN) dinv[i] = rsqrtf((float)v + 1.0f);   // +1 self-loop
  tmp[t] = v; __syncthreads();
  #pragma unroll
  for(int off=1; off<SCAN_BS; off<<=1){
    int x = (t >= off) ? tmp[t-off] : 0;
    __syncthreads();
    tmp[t] += x;
    __syncthreads();
  }
  if(i < nN) rowptr[i] = tmp[t] - v;
  if(t == SCAN_BS-1) blocksum[blockIdx.x] = tmp[t];
}
__global__ void k_scan2_bounds(int* __restrict__ blocksum, int nb,
                               const int* __restrict__ batch, int* __restrict__ gstart,
                               int nN, int nG){
  __shared__ int tmp[1024];
  const int t = threadIdx.x;
  int v = (t < nb) ? blocksum[t] : 0;
  tmp[t] = v; __syncthreads();
  #pragma unroll
  for(int off=1; off<1024; off<<=1){
    int x = (t >= off) ? tmp[t-off] : 0;
    __syncthreads();
    tmp[t] += x;
    __syncthreads();
  }
  if(t < nb) blocksum[t] = tmp[t] - v;
  if(t <= nG){
    int lo = 0, hi = nN;
    while(lo < hi){
      int mid = (lo + hi) >> 1;
      if(batch[mid] < t) lo = mid + 1; else hi = mid;
    }
    gstart[t] = lo;
  }
}
__global__ void k_scan3(int* __restrict__ rowptr, const int* __restrict__ blocksum,
                        int nN, int nE){
  const int i = blockIdx.x*SCAN_BS + threadIdx.x;
  if(i < nN) rowptr[i] += blocksum[blockIdx.x];
  if(i == 0) rowptr[nN] = nE;
}
__global__ void k_fill(const int* __restrict__ src, const int* __restrict__ tgt,
                       const int* __restrict__ rowptr, int* __restrict__ cursor,
                       int* __restrict__ csr_src, float* __restrict__ csr_w,
                       const float* __restrict__ dinv, int nE){
  int e = blockIdx.x*blockDim.x + threadIdx.x;
  if(e >= nE) return;
  int t = tgt[e];
  int s = src[e];
  int pos = rowptr[t] + atomicAdd(&cursor[t], 1);
  csr_src[pos] = s;
  csr_w[pos] = dinv[s] * dinv[t];
}
__global__ void k_transpose_cvt2(const float* __restrict__ W1, short* __restrict__ W1T,
                                 int K1, const float* __restrict__ W2, short* __restrict__ W2T,
                                 int K2, int N){
  int g = blockIdx.x*blockDim.x + threadIdx.x;
  const int t1 = K1*N;
  if(g < t1){
    int n = g / K1, k = g % K1;
    W1T[(size_t)n*K1 + k] = f2bf(W1[(size_t)k*N + n]);
  } else {
    g -= t1;
    if(g >= K2*N) return;
    int n = g / K2, k = g % K2;
    W2T[(size_t)n*K2 + k] = f2bf(W2[(size_t)k*N + n]);
  }
}

// ---- streaming GEMM, async-staged, counted-vmcnt ring (bf16 A, r11-verified) ----
// C[m][n] = sum_k A[m][k]*Bt[n][k]. 256 thr (4 waves), tile 128x128, K chunks of 32.
// D=2, NBUF=4 (64 KB LDS, 2 blocks/CU). Ring safety: writer slot (kc+2)%4 vs
// readers {kc-1,kc}%4 — distinct under <=1-iteration wave skew (one barrier/iter).
__global__ __launch_bounds__(256) void gemm_stream(const short* __restrict__ Ap,
    const short* __restrict__ Bt, short* __restrict__ C, int M, int N, int K)
{
  constexpr int D    = 2;
  constexpr int NBUF = 4;
  constexpr int IPC  = 4;                // 2 A + 2 B gld_lds per wave per chunk
  __shared__ __align__(16) char As[NBUF][128*64];  // 4x8KB
  __shared__ __align__(16) char Bs[NBUF][128*64];  // 4x8KB
  const int tid  = threadIdx.x;
  const int lane = tid & 63;
  const int wv   = tid >> 6;
  const int lr   = lane & 15;
  const int hi   = lane >> 4;
  const int blk_row = blockIdx.x * 128;
  const int blk_col = blockIdx.y * 128;
  const int nkc = K / 32;

  f4v acc[2][8];
  #pragma unroll
  for(int s=0;s<2;s++)
    #pragma unroll
    for(int nf=0;nf<8;nf++){ acc[s][nf][0]=0.f; acc[s][nf][1]=0.f; acc[s][nf][2]=0.f; acc[s][nf][3]=0.f; }

  const int w_ch = lane & 3;
  const int w_ro = lane >> 2;

  auto STAGE = [&](int kc, int buf){
    #pragma unroll
    for(int j=0; j<2; j++){
      const int base_row = wv*32 + j*16;
      const int lrow = base_row + w_ro;
      int grow = blk_row + lrow; if(grow >= M) grow = M-1;
      const int sch = w_ch ^ ((lrow>>1) & 3);
      const char* g = (const char*)Ap + ((size_t)grow*K + (size_t)kc*32)*2 + (sch<<4);
      gld_lds16(g, (void*)(As[buf] + base_row*64));
    }
    #pragma unroll
    for(int j=0; j<2; j++){
      const int base_row = wv*32 + j*16;
      const int lrow = base_row + w_ro;
      const int sch = w_ch ^ ((lrow>>1) & 3);
      const char* g = (const char*)Bt + ((size_t)(blk_col + lrow)*K + (size_t)kc*32)*2 + (sch<<4);
      gld_lds16(g, (void*)(Bs[buf] + base_row*64));
    }
  };

  #pragma unroll
  for(int p=0; p<D; p++) STAGE(p, p);

  for(int kc=0; kc<nkc; kc++){
    if(kc + D < nkc) STAGE(kc+D, (kc+D) % NBUF);
    const int rem = (nkc-1-kc < D ? nkc-1-kc : D) * IPC;
    if     (rem >= 8) asm volatile("s_waitcnt vmcnt(8)" ::: "memory");
    else if(rem >= 4) asm volatile("s_waitcnt vmcnt(4)" ::: "memory");
    else              asm volatile("s_waitcnt vmcnt(0)" ::: "memory");
    __builtin_amdgcn_s_barrier();
    __builtin_amdgcn_sched_barrier(0);

    const int buf = kc % NBUF;
    const char* ab = As[buf];
    const char* bb = Bs[buf];

    s8v a[2];
    #pragma unroll
    for(int s=0;s<2;s++){
      const int row = wv*32 + s*16 + lr;
      const int c = hi ^ ((row>>1) & 3);
      a[s] = *(const s8v*)(ab + row*64 + (c<<4));
    }

    #pragma unroll
    for(int nf=0;nf<8;nf++){
      const int brow = nf*16 + lr;
      const int c = hi ^ ((brow>>1) & 3);
      s8v bfr = *(const s8v*)(bb + brow*64 + (c<<4));
      acc[0][nf] = __builtin_amdgcn_mfma_f32_16x16x32_bf16(a[0], bfr, acc[0][nf], 0, 0, 0);
      acc[1][nf] = __builtin_amdgcn_mfma_f32_16x16x32_bf16(a[1], bfr, acc[1][nf], 0, 0, 0);
    }
  }

  #pragma unroll
  for(int s=0;s<2;s++){
    #pragma unroll
    for(int j=0;j<4;j++){
      const int row = blk_row + wv*32 + s*16 + hi*4 + j;
      if(row >= M) continue;
      #pragma unroll
      for(int nf=0;nf<8;nf++){
        const int col = blk_col + nf*16 + lr;
        C[(size_t)row*N + col] = f2bf(acc[s][nf][j]);
      }
    }
  }
}

// ---- fused aggregation: one wave per node, coalesced idx/weight prefetch + 8-deep gather ----
__global__ __launch_bounds__(256) void k_aggregate(
    const short* __restrict__ h, const float* __restrict__ dinv,
    const int* __restrict__ rowptr, const int* __restrict__ csr_src,
    const float* __restrict__ csr_w, const float* __restrict__ bias,
    short* __restrict__ hout, int nN)
{
  const int wave = threadIdx.x >> 6;
  const int lane = threadIdx.x & 63;
  const int node = blockIdx.x*4 + wave;
  if(node >= nN) return;
  const float di = dinv[node];
  const int beg = rowptr[node];
  const int deg = rowptr[node+1] - beg;

  s4v hv = *(const s4v*)&h[(size_t)node*256 + lane*4];
  const float d2 = di*di;
  f4v acc;
  #pragma unroll
  for(int j=0;j<4;j++) acc[j] = d2 * b2f(hv[j]);

  for(int base=0; base<deg; base+=64){
    const int cnt = min(deg - base, 64);
    int   myi = (lane < cnt) ? csr_src[beg + base + lane] : 0;
    float myw = (lane < cnt) ? csr_w[beg + base + lane] : 0.f;

    for(int p0=0; p0<cnt; p0+=8){
      s4v v[8]; float w[8]; int s[8];
      #pragma unroll
      for(int j=0;j<8;j++){
        int pp = p0 + j;
        int sl = (pp < cnt) ? pp : 0;
        s[j] = __shfl(myi, sl);
        w[j] = (pp < cnt) ? __shfl(myw, sl) : 0.f;
      }
      #pragma unroll
      for(int j=0;j<8;j++)
        v[j] = *(const s4v*)&h[(size_t)s[j]*256 + lane*4];
      #pragma unroll
      for(int j=0;j<8;j++){
        #pragma unroll
        for(int q=0;q<4;q++) acc[q] += w[j] * b2f(v[j][q]);
      }
    }
  }

  f4v bv = *(const f4v*)&bias[lane*4];
  s4v ov;
  #pragma unroll
  for(int j=0;j<4;j++) ov[j] = f2bf(fmaxf(acc[j]+bv[j], 0.f));
  *(s4v*)&hout[(size_t)node*256 + lane*4] = ov;
}

// ---- mean-pool: per-(graph,slice) partial sums, no atomics, no memset ----
#define POOL_SPLIT 8
__global__ __launch_bounds__(256) void k_pool(const short* __restrict__ h,
    const int* __restrict__ gstart, float* __restrict__ pool, int nG){
  const int g = blockIdx.x;
  const int sl = blockIdx.y;
  const int c = threadIdx.x;
  const int b = gstart[g], e = gstart[g+1];
  const int len = e - b;
  const int r0 = b + (int)((long long)len * sl / POOL_SPLIT);
  const int r1 = b + (int)((long long)len * (sl+1) / POOL_SPLIT);
  float acc = 0.f;
  for(int r=r0; r<r1; r++) acc += b2f(h[(size_t)r*256 + c]);
  pool[((size_t)g*POOL_SPLIT + sl)*256 + c] = acc;
}

__global__ void k_final(const float* __restrict__ pool, const int* __restrict__ gstart,
                        const float* __restrict__ Wp, const float* __restrict__ bp,
                        float* __restrict__ out, int HID_, int OUT_){
  __shared__ float mean[256];
  int g = blockIdx.x, j = threadIdx.x;
  float c = fmaxf((float)(gstart[g+1] - gstart[g]), 1.0f);
  for(int k=j; k<HID_; k+=blockDim.x){
    float s = 0.f;
    #pragma unroll
    for(int sl=0; sl<POOL_SPLIT; sl++)
      s += pool[((size_t)g*POOL_SPLIT + sl)*HID_ + k];
    mean[k] = s / c;
  }
  __syncthreads();
  float acc = bp[j];
  for(int k=0;k<HID_;k++) acc = fmaf(mean[k], Wp[(size_t)k*OUT_ + j], acc);
  out[(size_t)g*OUT_ + j] = acc;
}

extern "C" void kernel_launch(void* const* d_in, const int* in_sizes, int n_in,
                              void* d_out, int out_size, void* d_ws, size_t ws_size,
                              hipStream_t stream){
  const float* x   = (const float*)d_in[0];
  const int* ei    = (const int*)d_in[1];
  const int* batch = (const int*)d_in[2];
  const float* W1  = (const float*)d_in[3];
  const float* b1  = (const float*)d_in[4];
  const float* W2  = (const float*)d_in[5];
  const float* b2  = (const float*)d_in[6];
  const float* Wp  = (const float*)d_in[7];
  const float* bp  = (const float*)d_in[8];
  float* out = (float*)d_out;

  const int HID    = in_sizes[4];            // 256
  const int IN_DIM = in_sizes[3] / HID;      // 768
  const int OUT    = in_sizes[8];            // 128
  const int nE     = in_sizes[1] / 2;        // 300000
  const int nN     = in_sizes[2];            // 50000
  const int nG     = out_size / OUT;         // 64

  const int* src = ei;
  const int* tgt = ei + nE;

  char* w = (char*)d_ws;
  size_t off = 0;
  auto alloc = [&](size_t bytes)->char*{
    char* p = w + off; off += (bytes + 511) & ~(size_t)511; return p;
  };
  int*   deg     = (int*)  alloc((size_t)nN*4);      // deg+cursor adjacent: one memset
  int*   cursor  = (int*)  alloc((size_t)nN*4);
  float* dinv    = (float*)alloc((size_t)nN*4);
  int*   gstart  = (int*)  alloc((size_t)(nG+1)*4);
  float* pool    = (float*)alloc((size_t)nG*POOL_SPLIT*HID*4);
  int*   rowptr  = (int*)  alloc((size_t)(nN+1)*4);
  int*   csr_src = (int*)  alloc((size_t)nE*4);
  float* csr_w   = (float*)alloc((size_t)nE*4);
  int*   blocksum= (int*)  alloc((size_t)1024*4);
  short* W1T     = (short*)alloc((size_t)IN_DIM*HID*2);
  short* W2T     = (short*)alloc((size_t)HID*HID*2);
  short* xb      = (short*)alloc(((size_t)nN*IN_DIM + 4096)*2);
  short* h1      = (short*)alloc((size_t)(nN+128)*HID*2);
  short* h2      = (short*)alloc((size_t)(nN+128)*HID*2);
  (void)ws_size; (void)n_in;

  hipMemsetAsync(deg, 0, (size_t)((char*)cursor - (char*)deg) + (size_t)nN*4, stream);

  const int nb = (nN + SCAN_BS - 1) / SCAN_BS;
  k_convert<<<2048, 256, 0, stream>>>(x, xb, (long)nN*IN_DIM);
  k_deg <<<(nE+255)/256, 256, 0, stream>>>(tgt, deg, nE);
  k_scan1_dinv<<<nb, SCAN_BS, 0, stream>>>(deg, rowptr, blocksum, dinv, nN);
  k_scan2_bounds<<<1, 1024, 0, stream>>>(blocksum, nb, batch, gstart, nN, nG);
  k_scan3<<<nb, SCAN_BS, 0, stream>>>(rowptr, blocksum, nN, nE);
  k_fill <<<(nE+255)/256, 256, 0, stream>>>(src, tgt, rowptr, cursor, csr_src, csr_w, dinv, nE);
  k_transpose_cvt2<<<((IN_DIM+HID)*HID+255)/256, 256, 0, stream>>>(W1, W1T, IN_DIM, W2, W2T, HID, HID);

  dim3 gg((nN+127)/128, HID/128);
  const int nagg = (nN + 3) / 4;
  // layer 1 (bf16 A)
  gemm_stream<<<gg, 256, 0, stream>>>(xb, W1T, h2, nN, HID, IN_DIM);
  k_aggregate<<<nagg, 256, 0, stream>>>(h2, dinv, rowptr, csr_src, csr_w, b1, h1, nN);
  // layer 2
  gemm_stream<<<gg, 256, 0, stream>>>(h1, W2T, h2, nN, HID, HID);
  k_aggregate<<<nagg, 256, 0, stream>>>(h2, dinv, rowptr, csr_src, csr_w, b2, h1, nN);
  k_pool<<<dim3(nG, POOL_SPLIT), 256, 0, stream>>>(h1, gstart, pool, nG);
  // head
  k_final<<<nG, OUT, 0, stream>>>(pool, gstart, Wp, bp, out, HID, OUT);
}

// Round 14
// 250.235 us; speedup vs baseline: 1.1212x; 1.1130x over previous
//
#include <hip/hip_runtime.h>
#include <cstdint>
#include <cstddef>

typedef short s8v __attribute__((ext_vector_type(8)));
typedef short s4v __attribute__((ext_vector_type(4)));
typedef float f4v __attribute__((ext_vector_type(4)));

static __device__ __forceinline__ float b2f(short s){
  return __uint_as_float(((uint32_t)(uint16_t)s) << 16);
}
static __device__ __forceinline__ short f2bf(float f){
  uint32_t u = __float_as_uint(f);
  u = (u + 0x7fffu + ((u >> 16) & 1u)) >> 16;
  return (short)(uint16_t)u;
}

// ---- graph prep (fused) ----
__global__ void k_deg(const int* __restrict__ tgt, int* __restrict__ deg, int nE){
  int e = blockIdx.x*blockDim.x + threadIdx.x;
  if(e < nE) atomicAdd(&deg[tgt[e]], 1);
}

#define SCAN_BS 256
__global__ void k_scan1_dinv(const int* __restrict__ deg, int* __restrict__ rowptr,
                             int* __restrict__ blocksum, float* __restrict__ dinv, int nN){
  __shared__ int tmp[SCAN_BS];
  const int t = threadIdx.x;
  const int i = blockIdx.x*SCAN_BS + t;
  int v = (i < nN) ? deg[i] : 0;
  if(i < nN) dinv[i] = rsqrtf((float)v + 1.0f);   // +1 self-loop
  tmp[t] = v; __syncthreads();
  #pragma unroll
  for(int off=1; off<SCAN_BS; off<<=1){
    int x = (t >= off) ? tmp[t-off] : 0;
    __syncthreads();
    tmp[t] += x;
    __syncthreads();
  }
  if(i < nN) rowptr[i] = tmp[t] - v;
  if(t == SCAN_BS-1) blocksum[blockIdx.x] = tmp[t];
}
__global__ void k_scan2_bounds(int* __restrict__ blocksum, int nb,
                               const int* __restrict__ batch, int* __restrict__ gstart,
                               int nN, int nG){
  __shared__ int tmp[1024];
  const int t = threadIdx.x;
  int v = (t < nb) ? blocksum[t] : 0;
  tmp[t] = v; __syncthreads();
  #pragma unroll
  for(int off=1; off<1024; off<<=1){
    int x = (t >= off) ? tmp[t-off] : 0;
    __syncthreads();
    tmp[t] += x;
    __syncthreads();
  }
  if(t < nb) blocksum[t] = tmp[t] - v;
  if(t <= nG){
    int lo = 0, hi = nN;
    while(lo < hi){
      int mid = (lo + hi) >> 1;
      if(batch[mid] < t) lo = mid + 1; else hi = mid;
    }
    gstart[t] = lo;
  }
}
__global__ void k_scan3(int* __restrict__ rowptr, const int* __restrict__ blocksum,
                        int nN, int nE){
  const int i = blockIdx.x*SCAN_BS + threadIdx.x;
  if(i < nN) rowptr[i] += blocksum[blockIdx.x];
  if(i == 0) rowptr[nN] = nE;
}
__global__ void k_fill(const int* __restrict__ src, const int* __restrict__ tgt,
                       const int* __restrict__ rowptr, int* __restrict__ cursor,
                       int* __restrict__ csr_src, float* __restrict__ csr_w,
                       const float* __restrict__ dinv, int nE){
  int e = blockIdx.x*blockDim.x + threadIdx.x;
  if(e >= nE) return;
  int t = tgt[e];
  int s = src[e];
  int pos = rowptr[t] + atomicAdd(&cursor[t], 1);
  csr_src[pos] = s;
  csr_w[pos] = dinv[s] * dinv[t];
}
__global__ void k_transpose_cvt2(const float* __restrict__ W1, short* __restrict__ W1T,
                                 int K1, const float* __restrict__ W2, short* __restrict__ W2T,
                                 int K2, int N){
  int g = blockIdx.x*blockDim.x + threadIdx.x;
  const int t1 = K1*N;
  if(g < t1){
    int n = g / K1, k = g % K1;
    W1T[(size_t)n*K1 + k] = f2bf(W1[(size_t)k*N + n]);
  } else {
    g -= t1;
    if(g >= K2*N) return;
    int n = g / K2, k = g % K2;
    W2T[(size_t)n*K2 + k] = f2bf(W2[(size_t)k*N + n]);
  }
}

// ---- streaming GEMM: REG-staged (T14 issue-early/write-late), NBUF=2 ----
// C[m][n] = sum_k A[m][k]*Bt[n][k]. 256 thr (4 waves), tile 128x128, KC=32.
// Staging via ordinary global_load_dwordx4 -> VGPR (deep HW queues, per-wave
// run-ahead) then swizzled ds_write; f32->bf16 convert happens in-reg in the
// staging path. Barriers are raw s_barrier with lgkmcnt(0) ONLY — global
// loads for chunk kc+2 stay in flight across the barrier.
// Iter kc: compute(kc) | vmcnt(0) [loads(kc+1) landed, hidden under compute]
//          | ds_write(kc+1) slot (kc+1)&1 | issue loads(kc+2) | lgkm+barrier.
// NBUF=2 safety: writes to slot (kc+1)&1 occur between barrier(kc) and
// barrier(kc+1); every wave in that window reads slot kc&1 only. LDS 32 KB.
template<bool AF32>
__global__ __launch_bounds__(256) void gemm_stream(const void* __restrict__ Ap,
    const short* __restrict__ Bt, short* __restrict__ C, int M, int N, int K)
{
  __shared__ __align__(16) short As[2][128*32];   // bf16 8 KB per buf
  __shared__ __align__(16) short Bs[2][128*32];
  const int tid  = threadIdx.x;
  const int lane = tid & 63;
  const int wv   = tid >> 6;
  const int lr   = lane & 15;
  const int hi   = lane >> 4;
  const int blk_row = blockIdx.x * 128;
  const int blk_col = blockIdx.y * 128;
  const int nkc = K / 32;

  f4v acc[2][8];
  #pragma unroll
  for(int s=0;s<2;s++)
    #pragma unroll
    for(int nf=0;nf<8;nf++){ acc[s][nf][0]=0.f; acc[s][nf][1]=0.f; acc[s][nf][2]=0.f; acc[s][nf][3]=0.f; }

  // ---- staging lane geometry ----
  // A(f32):  4 instr, lane -> row wv*32+j*8+(lane>>3), 16B = 4 k-elems at slot lane&7
  // A(bf16)/B: 2 instr, lane -> row wv*32+j*16+(lane>>2), 16B = 8 k-elems at slot lane&3
  f4v ar[4];            // A f32 staging regs
  s8v ab2[2];           // A bf16 staging regs
  s8v br[2];            // B staging regs

  auto LOAD = [&](int kc){
    if constexpr(AF32){
      #pragma unroll
      for(int j=0;j<4;j++){
        const int lrow = wv*32 + j*8 + (lane>>3);
        int grow = blk_row + lrow; if(grow >= M) grow = M-1;
        ar[j] = *(const f4v*)((const char*)Ap + ((size_t)grow*K + (size_t)kc*32)*4 + ((lane&7)<<4));
      }
    } else {
      #pragma unroll
      for(int j=0;j<2;j++){
        const int lrow = wv*32 + j*16 + (lane>>2);
        int grow = blk_row + lrow; if(grow >= M) grow = M-1;
        ab2[j] = *(const s8v*)((const char*)Ap + ((size_t)grow*K + (size_t)kc*32)*2 + ((lane&3)<<4));
      }
    }
    #pragma unroll
    for(int j=0;j<2;j++){
      const int lrow = wv*32 + j*16 + (lane>>2);
      br[j] = *(const s8v*)((const char*)Bt + ((size_t)(blk_col+lrow)*K + (size_t)kc*32)*2 + ((lane&3)<<4));
    }
  };
  auto WRITE = [&](int buf){
    if constexpr(AF32){
      #pragma unroll
      for(int j=0;j<4;j++){
        const int lrow = wv*32 + j*8 + (lane>>3);
        const int sl = lane & 7;
        const int c = (sl>>1) ^ ((lrow>>1)&3);
        s4v v;
        #pragma unroll
        for(int q=0;q<4;q++) v[q] = f2bf(ar[j][q]);
        *(s4v*)(&As[buf][lrow*32 + c*8 + (sl&1)*4]) = v;
      }
    } else {
      #pragma unroll
      for(int j=0;j<2;j++){
        const int lrow = wv*32 + j*16 + (lane>>2);
        const int c = (lane&3) ^ ((lrow>>1)&3);
        *(s8v*)(&As[buf][lrow*32 + c*8]) = ab2[j];
      }
    }
    #pragma unroll
    for(int j=0;j<2;j++){
      const int lrow = wv*32 + j*16 + (lane>>2);
      const int c = (lane&3) ^ ((lrow>>1)&3);
      *(s8v*)(&Bs[buf][lrow*32 + c*8]) = br[j];
    }
  };

  // prologue
  LOAD(0);
  asm volatile("s_waitcnt vmcnt(0)" ::: "memory");
  WRITE(0);
  if(nkc > 1) LOAD(1);
  asm volatile("s_waitcnt lgkmcnt(0)" ::: "memory");
  __builtin_amdgcn_s_barrier();
  __builtin_amdgcn_sched_barrier(0);

  for(int kc=0; kc<nkc; kc++){
    const char* ab = (const char*)&As[kc&1][0];
    const char* bb = (const char*)&Bs[kc&1][0];

    s8v a[2];
    #pragma unroll
    for(int s=0;s<2;s++){
      const int row = wv*32 + s*16 + lr;
      const int c = hi ^ ((row>>1) & 3);
      a[s] = *(const s8v*)(ab + row*64 + (c<<4));
    }
    #pragma unroll
    for(int nf=0;nf<8;nf++){
      const int brow = nf*16 + lr;
      const int c = hi ^ ((brow>>1) & 3);
      s8v bfr = *(const s8v*)(bb + brow*64 + (c<<4));
      acc[0][nf] = __builtin_amdgcn_mfma_f32_16x16x32_bf16(a[0], bfr, acc[0][nf], 0, 0, 0);
      acc[1][nf] = __builtin_amdgcn_mfma_f32_16x16x32_bf16(a[1], bfr, acc[1][nf], 0, 0, 0);
    }

    if(kc+1 < nkc){
      asm volatile("s_waitcnt vmcnt(0)" ::: "memory");   // loads(kc+1) landed (hidden under compute)
      WRITE((kc+1)&1);
      if(kc+2 < nkc) LOAD(kc+2);                          // stays in flight across barrier
    }
    asm volatile("s_waitcnt lgkmcnt(0)" ::: "memory");    // ds_writes visible
    __builtin_amdgcn_s_barrier();
    __builtin_amdgcn_sched_barrier(0);
  }

  #pragma unroll
  for(int s=0;s<2;s++){
    #pragma unroll
    for(int j=0;j<4;j++){
      const int row = blk_row + wv*32 + s*16 + hi*4 + j;
      if(row >= M) continue;
      #pragma unroll
      for(int nf=0;nf<8;nf++){
        const int col = blk_col + nf*16 + lr;
        C[(size_t)row*N + col] = f2bf(acc[s][nf][j]);
      }
    }
  }
}

// ---- fused aggregation: one wave per node, coalesced idx/weight prefetch + 8-deep gather ----
__global__ __launch_bounds__(256) void k_aggregate(
    const short* __restrict__ h, const float* __restrict__ dinv,
    const int* __restrict__ rowptr, const int* __restrict__ csr_src,
    const float* __restrict__ csr_w, const float* __restrict__ bias,
    short* __restrict__ hout, int nN)
{
  const int wave = threadIdx.x >> 6;
  const int lane = threadIdx.x & 63;
  const int node = blockIdx.x*4 + wave;
  if(node >= nN) return;
  const float di = dinv[node];
  const int beg = rowptr[node];
  const int deg = rowptr[node+1] - beg;

  s4v hv = *(const s4v*)&h[(size_t)node*256 + lane*4];
  const float d2 = di*di;
  f4v acc;
  #pragma unroll
  for(int j=0;j<4;j++) acc[j] = d2 * b2f(hv[j]);

  for(int base=0; base<deg; base+=64){
    const int cnt = min(deg - base, 64);
    int   myi = (lane < cnt) ? csr_src[beg + base + lane] : 0;
    float myw = (lane < cnt) ? csr_w[beg + base + lane] : 0.f;

    for(int p0=0; p0<cnt; p0+=8){
      s4v v[8]; float w[8]; int s[8];
      #pragma unroll
      for(int j=0;j<8;j++){
        int pp = p0 + j;
        int sl = (pp < cnt) ? pp : 0;
        s[j] = __shfl(myi, sl);
        w[j] = (pp < cnt) ? __shfl(myw, sl) : 0.f;
      }
      #pragma unroll
      for(int j=0;j<8;j++)
        v[j] = *(const s4v*)&h[(size_t)s[j]*256 + lane*4];
      #pragma unroll
      for(int j=0;j<8;j++){
        #pragma unroll
        for(int q=0;q<4;q++) acc[q] += w[j] * b2f(v[j][q]);
      }
    }
  }

  f4v bv = *(const f4v*)&bias[lane*4];
  s4v ov;
  #pragma unroll
  for(int j=0;j<4;j++) ov[j] = f2bf(fmaxf(acc[j]+bv[j], 0.f));
  *(s4v*)&hout[(size_t)node*256 + lane*4] = ov;
}

// ---- mean-pool: per-(graph,slice) partial sums, no atomics, no memset ----
#define POOL_SPLIT 8
__global__ __launch_bounds__(256) void k_pool(const short* __restrict__ h,
    const int* __restrict__ gstart, float* __restrict__ pool, int nG){
  const int g = blockIdx.x;
  const int sl = blockIdx.y;
  const int c = threadIdx.x;
  const int b = gstart[g], e = gstart[g+1];
  const int len = e - b;
  const int r0 = b + (int)((long long)len * sl / POOL_SPLIT);
  const int r1 = b + (int)((long long)len * (sl+1) / POOL_SPLIT);
  float acc = 0.f;
  for(int r=r0; r<r1; r++) acc += b2f(h[(size_t)r*256 + c]);
  pool[((size_t)g*POOL_SPLIT + sl)*256 + c] = acc;
}

__global__ void k_final(const float* __restrict__ pool, const int* __restrict__ gstart,
                        const float* __restrict__ Wp, const float* __restrict__ bp,
                        float* __restrict__ out, int HID_, int OUT_){
  __shared__ float mean[256];
  int g = blockIdx.x, j = threadIdx.x;
  float c = fmaxf((float)(gstart[g+1] - gstart[g]), 1.0f);
  for(int k=j; k<HID_; k+=blockDim.x){
    float s = 0.f;
    #pragma unroll
    for(int sl=0; sl<POOL_SPLIT; sl++)
      s += pool[((size_t)g*POOL_SPLIT + sl)*HID_ + k];
    mean[k] = s / c;
  }
  __syncthreads();
  float acc = bp[j];
  for(int k=0;k<HID_;k++) acc = fmaf(mean[k], Wp[(size_t)k*OUT_ + j], acc);
  out[(size_t)g*OUT_ + j] = acc;
}

extern "C" void kernel_launch(void* const* d_in, const int* in_sizes, int n_in,
                              void* d_out, int out_size, void* d_ws, size_t ws_size,
                              hipStream_t stream){
  const float* x   = (const float*)d_in[0];
  const int* ei    = (const int*)d_in[1];
  const int* batch = (const int*)d_in[2];
  const float* W1  = (const float*)d_in[3];
  const float* b1  = (const float*)d_in[4];
  const float* W2  = (const float*)d_in[5];
  const float* b2  = (const float*)d_in[6];
  const float* Wp  = (const float*)d_in[7];
  const float* bp  = (const float*)d_in[8];
  float* out = (float*)d_out;

  const int HID    = in_sizes[4];            // 256
  const int IN_DIM = in_sizes[3] / HID;      // 768
  const int OUT    = in_sizes[8];            // 128
  const int nE     = in_sizes[1] / 2;        // 300000
  const int nN     = in_sizes[2];            // 50000
  const int nG     = out_size / OUT;         // 64

  const int* src = ei;
  const int* tgt = ei + nE;

  char* w = (char*)d_ws;
  size_t off = 0;
  auto alloc = [&](size_t bytes)->char*{
    char* p = w + off; off += (bytes + 511) & ~(size_t)511; return p;
  };
  int*   deg     = (int*)  alloc((size_t)nN*4);      // deg+cursor adjacent: one memset
  int*   cursor  = (int*)  alloc((size_t)nN*4);
  float* dinv    = (float*)alloc((size_t)nN*4);
  int*   gstart  = (int*)  alloc((size_t)(nG+1)*4);
  float* pool    = (float*)alloc((size_t)nG*POOL_SPLIT*HID*4);
  int*   rowptr  = (int*)  alloc((size_t)(nN+1)*4);
  int*   csr_src = (int*)  alloc((size_t)nE*4);
  float* csr_w   = (float*)alloc((size_t)nE*4);
  int*   blocksum= (int*)  alloc((size_t)1024*4);
  short* W1T     = (short*)alloc((size_t)IN_DIM*HID*2);
  short* W2T     = (short*)alloc((size_t)HID*HID*2);
  short* h1      = (short*)alloc((size_t)(nN+128)*HID*2);
  short* h2      = (short*)alloc((size_t)(nN+128)*HID*2);
  (void)ws_size; (void)n_in;

  hipMemsetAsync(deg, 0, (size_t)((char*)cursor - (char*)deg) + (size_t)nN*4, stream);

  const int nb = (nN + SCAN_BS - 1) / SCAN_BS;
  k_deg <<<(nE+255)/256, 256, 0, stream>>>(tgt, deg, nE);
  k_scan1_dinv<<<nb, SCAN_BS, 0, stream>>>(deg, rowptr, blocksum, dinv, nN);
  k_scan2_bounds<<<1, 1024, 0, stream>>>(blocksum, nb, batch, gstart, nN, nG);
  k_scan3<<<nb, SCAN_BS, 0, stream>>>(rowptr, blocksum, nN, nE);
  k_fill <<<(nE+255)/256, 256, 0, stream>>>(src, tgt, rowptr, cursor, csr_src, csr_w, dinv, nE);
  k_transpose_cvt2<<<((IN_DIM+HID)*HID+255)/256, 256, 0, stream>>>(W1, W1T, IN_DIM, W2, W2T, HID, HID);

  dim3 gg((nN+127)/128, HID/128);
  const int nagg = (nN + 3) / 4;
  // layer 1 (f32 A, converted in staging regs)
  gemm_stream<true><<<gg, 256, 0, stream>>>(x, W1T, h2, nN, HID, IN_DIM);
  k_aggregate<<<nagg, 256, 0, stream>>>(h2, dinv, rowptr, csr_src, csr_w, b1, h1, nN);
  // layer 2 (bf16 A)
  gemm_stream<false><<<gg, 256, 0, stream>>>(h1, W2T, h2, nN, HID, HID);
  k_aggregate<<<nagg, 256, 0, stream>>>(h2, dinv, rowptr, csr_src, csr_w, b2, h1, nN);
  k_pool<<<dim3(nG, POOL_SPLIT), 256, 0, stream>>>(h1, gstart, pool, nG);
  // head
  k_final<<<nG, OUT, 0, stream>>>(pool, gstart, Wp, bp, out, HID, OUT);
}